// Round 3
// 775.449 us; speedup vs baseline: 1.4354x; 1.4354x over previous
//
#include <hip/hip_runtime.h>
#include <math.h>

// CrossAttentionLayer_two_level — split design for MI355X (gfx950).
//  prep_kernel : folds LN+Wq+Wk into QW (64x128 bf16) + qb (as before).
//  conv_kernel : one-time fp32->bf16 prefold of Wv/Wp/Wf1/Wf2 into d_ws.
//  attn_kernel : 1 block/batch, ONE barrier. dots/v MFMA -> in-reg softmax ->
//                wave-private P/vT LDS roundtrip (no barrier) -> PV (BOTH
//                n-quadrants; valid one selected at the STORE — B-fragment
//                columns must not depend on the lane's k-slice g!) ->
//                act written fp32 IN-PLACE into out.
//  mlp_kernel  : barrier-free. 64 rows (=8 batches)/block, wave owns 16 rows;
//                Wp+residual -> LN (wave-local shfl) -> Wf1+gelu -> Wf2 ->
//                out = x + y, overwriting the act rows it read.

typedef __bf16 v8bf __attribute__((ext_vector_type(8)));
typedef float  v4f  __attribute__((ext_vector_type(4)));

static __device__ __forceinline__ v4f mfma16(v8bf a, v8bf b, v4f c) {
  return __builtin_amdgcn_mfma_f32_16x16x32_bf16(a, b, c, 0, 0, 0);
}

static __device__ __forceinline__ v8bf cvt8(const float* __restrict__ p) {
  float4 a = *(const float4*)p;
  float4 b = *(const float4*)(p + 4);
  v8bf f;
  f[0] = (__bf16)a.x; f[1] = (__bf16)a.y; f[2] = (__bf16)a.z; f[3] = (__bf16)a.w;
  f[4] = (__bf16)b.x; f[5] = (__bf16)b.y; f[6] = (__bf16)b.z; f[7] = (__bf16)b.w;
  return f;
}

// ---------------- prep: q = LN(query)@Wq.T + bq;  QW[c=h*8+i] = 0.25*Wk_h^T q_h[i]
__global__ __launch_bounds__(256)
void prep_kernel(const float* __restrict__ query,
                 const float* __restrict__ g1, const float* __restrict__ b1,
                 const float* __restrict__ Wq, const float* __restrict__ bq,
                 const float* __restrict__ Wk, const float* __restrict__ bk,
                 __bf16* __restrict__ qw, float* __restrict__ qb)
{
  __shared__ float qn[8*128];
  __shared__ float qp[8*128];
  const int t = threadIdx.x;
  for (int idx = t; idx < 1024; idx += 256) qn[idx] = query[idx];
  __syncthreads();
  {
    const int w = t >> 6, L = t & 63;
    const int row = 2*w + (L >> 5), col = L & 31;
    float x[4], s = 0.f, sq = 0.f;
    for (int p = 0; p < 4; p++) { x[p] = qn[row*128 + col + 32*p]; s += x[p]; sq += x[p]*x[p]; }
    for (int m = 1; m < 32; m <<= 1) { s += __shfl_xor(s, m); sq += __shfl_xor(sq, m); }
    const float mean = s * (1.f/128.f);
    const float var  = sq * (1.f/128.f) - mean*mean;
    const float rs   = rsqrtf(var + 1e-5f);
    for (int p = 0; p < 4; p++) {
      const int e = col + 32*p;
      qn[row*128 + e] = (x[p]-mean)*rs*g1[e] + b1[e];
    }
  }
  __syncthreads();
  {
    const int i = t >> 5, o0 = t & 31;
    for (int p = 0; p < 4; p++) {
      const int o = o0 + 32*p;
      float acc = bq[o];
      for (int e = 0; e < 128; e++) acc += qn[i*128 + e] * Wq[o*128 + e];
      qp[i*128 + o] = acc;
    }
  }
  __syncthreads();
  {
    const int cc = t >> 2, e0 = (t & 3) * 32;
    const int h = cc >> 3, i = cc & 7;
    float qv[16];
    for (int d = 0; d < 16; d++) qv[d] = qp[i*128 + 16*h + d];
    for (int e = e0; e < e0 + 32; e++) {
      float acc = 0.f;
      for (int d = 0; d < 16; d++) acc += qv[d] * Wk[(16*h + d)*128 + e];
      qw[cc*136 + e] = (__bf16)(0.25f * acc);
    }
    if (t < 64) {
      const int h2 = t >> 3, i2 = t & 7;
      float acc = 0.f;
      for (int d = 0; d < 16; d++) acc += qp[i2*128 + 16*h2 + d] * bk[16*h2 + d];
      qb[t] = 0.25f * acc;
    }
  }
}

// ---------------- one-time weight prefold to bf16 (4 blocks, one matrix each)
__global__ __launch_bounds__(256)
void conv_kernel(const float* __restrict__ Wv, const float* __restrict__ Wp,
                 const float* __restrict__ Wf1, const float* __restrict__ Wf2,
                 __bf16* __restrict__ dst)
{
  const int m = blockIdx.x;
  const float* src = (m == 0) ? Wv : (m == 1) ? Wp : (m == 2) ? Wf1 : Wf2;
  __bf16* d = dst + m*16384;
  for (int i = threadIdx.x; i < 2048; i += 256)
    *(v8bf*)&d[i*8] = cvt8(&src[i*8]);
}

// ---------------- attention: one block per batch, ONE barrier
__global__ __launch_bounds__(256, 4)
void attn_kernel(const float* __restrict__ tgt,
                 const float* __restrict__ bv,
                 const __bf16* __restrict__ qw,
                 const float* __restrict__ qb,
                 const __bf16* __restrict__ wv,
                 float* __restrict__ xout)   // act written fp32 into out buffer
{
  __shared__ __align__(16) __bf16 s_tgt[48*136];   // [j][e]   A-operand
  __shared__ __align__(16) __bf16 s_P[64*72];      // [c][j]   wave-private rows
  __shared__ __align__(16) __bf16 s_vT[128*72];    // [o][j]   wave-private rows

  const int b  = blockIdx.x;
  const int t  = threadIdx.x;
  const int w  = t >> 6;       // wave 0..3
  const int L  = t & 63;
  const int ln = L & 15;       // MFMA m/n lane
  const int g  = L >> 4;       // quad (k-slice index!)

  // wave-local zero of the j-pad [48,64) in the rows this wave owns
  for (int p = 0; p < 8; p++) {
    const int idx = 64*p + L;                     // 0..511
    s_vT[(w*32 + (idx >> 4))*72 + 48 + (idx & 15)] = (__bf16)0.f;
  }
  for (int p = 0; p < 4; p++) {
    const int idx = 64*p + L;                     // 0..255
    s_P[(w*16 + (idx >> 4))*72 + 48 + (idx & 15)] = (__bf16)0.f;
  }

  // stage tgt tile (fp32 -> bf16) — the only block-wide shared data
  {
    const float* tg = tgt + (long)b * 6144;
    for (int c8 = t; c8 < 768; c8 += 256) {
      v8bf v = cvt8(&tg[c8*8]);
      *(v8bf*)&s_tgt[(c8 >> 4)*136 + (c8 & 15)*8] = v;
    }
  }
  __syncthreads();

  const int c = w*16 + ln;     // dots column (h*8+i); wave w owns c-range

  // dots = tgt@QW.T  and  v = tgt@Wv.T  (Wv prefolded bf16)
  v4f dacc[3], vacc[3][2];
  {
    v8bf qwf[4], wvf[2][4];
    for (int ks = 0; ks < 4; ks++)
      qwf[ks] = *(const v8bf*)&qw[c*136 + ks*32 + g*8];
    for (int nt = 0; nt < 2; nt++)
      for (int ks = 0; ks < 4; ks++)
        wvf[nt][ks] = *(const v8bf*)&wv[(w*32 + nt*16 + ln)*128 + ks*32 + g*8];
    const v4f z = {0.f, 0.f, 0.f, 0.f};
    for (int mt = 0; mt < 3; mt++) { dacc[mt] = z; vacc[mt][0] = z; vacc[mt][1] = z; }
    for (int mt = 0; mt < 3; mt++) {
      v8bf af[4];
      for (int ks = 0; ks < 4; ks++)
        af[ks] = *(const v8bf*)&s_tgt[(mt*16 + ln)*136 + ks*32 + g*8];
      for (int ks = 0; ks < 4; ks++) {
        dacc[mt]    = mfma16(af[ks], qwf[ks],    dacc[mt]);
        vacc[mt][0] = mfma16(af[ks], wvf[0][ks], vacc[mt][0]);
        vacc[mt][1] = mfma16(af[ks], wvf[1][ks], vacc[mt][1]);
      }
    }
  }

  // softmax over j (window-masked) -> write wave-private P and vT
  {
    const int i = c & 7;
    const float qbv = qb[c];
    const bool allv = (i < 2);
    int hsp = 0, wsp = 0;
    if (!allv) { const int idx = i - 2; hsp = idx / 3; wsp = idx - 3*hsp; }
    float dv[12];
    float mx = -1e30f;
    for (int mt = 0; mt < 3; mt++)
      for (int r = 0; r < 4; r++) {
        const int j  = mt*16 + g*4 + r;
        const int rr = j / 6, ccol = j - rr*6;
        const bool valid = allv || (((rr >> 2) == hsp) && ((ccol >> 1) == wsp));
        const float dd = valid ? dacc[mt][r] + qbv : -1e30f;
        dv[mt*4 + r] = dd;
        mx = fmaxf(mx, dd);
      }
    mx = fmaxf(mx, __shfl_xor(mx, 16));
    mx = fmaxf(mx, __shfl_xor(mx, 32));
    float sm = 0.f;
    for (int p = 0; p < 12; p++) {
      const float e = (dv[p] > -1e29f) ? __expf(dv[p] - mx) : 0.f;
      dv[p] = e; sm += e;
    }
    sm += __shfl_xor(sm, 16);
    sm += __shfl_xor(sm, 32);
    const float inv = 1.f / sm;
    for (int mt = 0; mt < 3; mt++)
      for (int r = 0; r < 4; r++)
        s_P[c*72 + mt*16 + g*4 + r] = (__bf16)(dv[mt*4 + r] * inv);
    for (int nt = 0; nt < 2; nt++) {
      const int o = w*32 + nt*16 + ln;
      const float bvo = bv[o];
      for (int mt = 0; mt < 3; mt++)
        for (int r = 0; r < 4; r++)
          s_vT[o*72 + mt*16 + g*4 + r] = (__bf16)(vacc[mt][nt][r] + bvo);
    }
  }
  // NO barrier: s_P rows [16w,16w+16) and s_vT rows [32w,32w+32) are wave-private.

  // PV — compute BOTH n-quadrants (B-fragment col must be g-independent),
  // select the valid one per-lane at the store.
  {
    const v4f z = {0.f,0.f,0.f,0.f};
    v4f oacc[2] = {z, z};
    for (int ks = 0; ks < 2; ks++) {
      v8bf pf = *(const v8bf*)&s_P[(w*16 + ln)*72 + ks*32 + g*8];
      for (int nt = 0; nt < 2; nt++) {
        v8bf vf = *(const v8bf*)&s_vT[(w*32 + nt*16 + ln)*72 + ks*32 + g*8];
        oacc[nt] = mfma16(pf, vf, oacc[nt]);
      }
    }
    const int ntv = g >> 1;                 // head of rows g*4+r matches col chunk
    const int o = w*32 + ntv*16 + ln;
    float* xo = xout + (long)b * 1024;
    for (int r = 0; r < 4; r++) {
      const int i = (g*4 + r) & 7;
      xo[i*128 + o] = oacc[ntv][r];
    }
  }
}

// ---------------- MLP: barrier-free, 64 rows/block, wave owns 16 rows (2 batches)
__global__ __launch_bounds__(256, 4)
void mlp_kernel(const float* __restrict__ query,
                const float* __restrict__ bp,
                const float* __restrict__ g2, const float* __restrict__ b2,
                const float* __restrict__ bf1, const float* __restrict__ bf2,
                const __bf16* __restrict__ wp,
                const __bf16* __restrict__ wf1,
                const __bf16* __restrict__ wf2,
                float* __restrict__ xio)     // in: act rows; out: final (in-place)
{
  __shared__ __align__(16) __bf16 s_xn[4][16*136];
  __shared__ __align__(16) __bf16 s_h [4][16*136];

  const int t  = threadIdx.x;
  const int w  = t >> 6, L = t & 63;
  const int ln = L & 15, g = L >> 4;
  const long row0 = (long)blockIdx.x*64 + w*16;   // multiple of 16 -> i = (4g+r)&7
  float* base = xio + row0*128;

  // A-fragments of act (fp32 -> bf16); reads complete before in-place stores below
  v8bf af[4];
  for (int ks = 0; ks < 4; ks++)
    af[ks] = cvt8(&base[ln*128 + ks*32 + g*8]);

  // GEMM1: x = act@Wp.T + bp + query   (D-layout: row 4g+r, col nt*16+ln)
  float x[8][4];
  for (int nt = 0; nt < 8; nt++) {
    v4f acc = {0.f, 0.f, 0.f, 0.f};
    for (int ks = 0; ks < 4; ks++) {
      v8bf wf = *(const v8bf*)&wp[(nt*16 + ln)*128 + ks*32 + g*8];
      acc = mfma16(af[ks], wf, acc);
    }
    const int col = nt*16 + ln;
    const float bpv = bp[col];
    for (int r = 0; r < 4; r++)
      x[nt][r] = acc[r] + bpv + query[((4*g + r) & 7)*128 + col];
  }

  // LN per row (rows 4g+r are wave-local: reduce over nt then 16 lanes)
  float rmean[4], rrs[4];
  for (int r = 0; r < 4; r++) {
    float s = 0.f, sq = 0.f;
    for (int nt = 0; nt < 8; nt++) { s += x[nt][r]; sq += x[nt][r]*x[nt][r]; }
    for (int m = 1; m < 16; m <<= 1) { s += __shfl_xor(s, m); sq += __shfl_xor(sq, m); }
    const float mean = s * (1.f/128.f);
    const float var  = sq * (1.f/128.f) - mean*mean;
    rmean[r] = mean;
    rrs[r]   = rsqrtf(var + 1e-5f);
  }
  for (int nt = 0; nt < 8; nt++) {
    const int col = nt*16 + ln;
    const float gv = g2[col], b2v = b2[col];
    for (int r = 0; r < 4; r++)
      s_xn[w][(4*g + r)*136 + col] = (__bf16)((x[nt][r] - rmean[r])*rrs[r]*gv + b2v);
  }
  // wave-private transpose roundtrip (no barrier; lgkmcnt orders write->read)
  v8bf xf[4];
  for (int ks = 0; ks < 4; ks++)
    xf[ks] = *(const v8bf*)&s_xn[w][ln*136 + ks*32 + g*8];

  // GEMM2: h = gelu(xn@Wf1.T + bf1)
  for (int nt = 0; nt < 8; nt++) {
    v4f acc = {0.f, 0.f, 0.f, 0.f};
    for (int ks = 0; ks < 4; ks++) {
      v8bf wf = *(const v8bf*)&wf1[(nt*16 + ln)*128 + ks*32 + g*8];
      acc = mfma16(xf[ks], wf, acc);
    }
    const int col = nt*16 + ln;
    const float b1v = bf1[col];
    for (int r = 0; r < 4; r++) {
      const float xx = acc[r] + b1v;
      s_h[w][(4*g + r)*136 + col] = (__bf16)(0.5f*xx*(1.f + erff(xx*0.70710678118654752f)));
    }
  }
  v8bf hf[4];
  for (int ks = 0; ks < 4; ks++)
    hf[ks] = *(const v8bf*)&s_h[w][ln*136 + ks*32 + g*8];

  // GEMM3: y = h@Wf2.T + bf2 ; out = x + y (in-place over the act rows we read)
  for (int nt = 0; nt < 8; nt++) {
    v4f acc = {0.f, 0.f, 0.f, 0.f};
    for (int ks = 0; ks < 4; ks++) {
      v8bf wf = *(const v8bf*)&wf2[(nt*16 + ln)*128 + ks*32 + g*8];
      acc = mfma16(hf[ks], wf, acc);
    }
    const int col = nt*16 + ln;
    const float b2v = bf2[col];
    for (int r = 0; r < 4; r++)
      base[(4*g + r)*128 + col] = x[nt][r] + acc[r] + b2v;
  }
}

extern "C" void kernel_launch(void* const* d_in, const int* in_sizes, int n_in,
                              void* d_out, int out_size, void* d_ws, size_t ws_size,
                              hipStream_t stream)
{
  const float* query = (const float*)d_in[0];
  const float* tgt   = (const float*)d_in[1];
  const float* g1    = (const float*)d_in[2];
  const float* b1    = (const float*)d_in[3];
  const float* Wq    = (const float*)d_in[4];
  const float* bq    = (const float*)d_in[5];
  const float* Wk    = (const float*)d_in[6];
  const float* bk    = (const float*)d_in[7];
  const float* Wv    = (const float*)d_in[8];
  const float* bv    = (const float*)d_in[9];
  const float* Wp    = (const float*)d_in[10];
  const float* bp    = (const float*)d_in[11];
  const float* g2    = (const float*)d_in[12];
  const float* b2    = (const float*)d_in[13];
  const float* Wf1   = (const float*)d_in[14];
  const float* bf1   = (const float*)d_in[15];
  const float* Wf2   = (const float*)d_in[16];
  const float* bf2   = (const float*)d_in[17];
  float* out = (float*)d_out;

  // workspace: qw (64x136 bf16) | qb (64 f32) | Wv,Wp,Wf1,Wf2 prefolded bf16
  __bf16* qw  = (__bf16*)d_ws;                           // 17408 B
  float*  qb  = (float*)((char*)d_ws + 64*136*2);        // 256 B
  __bf16* wbf = (__bf16*)((char*)d_ws + 64*136*2 + 256); // 4 * 32768 B (16B-aligned)

  const int nB = in_sizes[1] / (48 * 128);               // 16384

  prep_kernel<<<1, 256, 0, stream>>>(query, g1, b1, Wq, bq, Wk, bk, qw, qb);
  conv_kernel<<<4, 256, 0, stream>>>(Wv, Wp, Wf1, Wf2, wbf);
  attn_kernel<<<nB, 256, 0, stream>>>(tgt, bv, qw, qb, wbf /*Wv*/, out);
  mlp_kernel<<<nB/8, 256, 0, stream>>>(query, bp, g2, b2, bf1, bf2,
                                       wbf + 16384, wbf + 2*16384, wbf + 3*16384,
                                       out);
}

// Round 4
// 709.609 us; speedup vs baseline: 1.5686x; 1.0928x over previous
//
#include <hip/hip_runtime.h>
#include <math.h>

// CrossAttentionLayer_two_level — fully fused streaming design for MI355X (gfx950).
//  prep_conv_kernel : blocks 0-3 prefold Wv/Wp/Wf1/Wf2 to bf16; block 4 folds
//                     LN+Wq+Wk into QW (64x128 bf16) + qb.
//  fused2_kernel    : 8 batches per block. Per batch: reg-prefetched tgt stage
//                     (double-buffered LDS, ONE barrier) -> dots/v MFMA ->
//                     in-reg softmax -> wave-private P/vT LDS roundtrip ->
//                     PV (both n-quadrants, valid one selected at store) ->
//                     act (bf16) into LDS. Then one barrier and the barrier-free
//                     MLP (Wp+residual -> LN -> Wf1+gelu -> Wf2 -> out) runs on
//                     the 64 hot act rows. act never touches HBM.

typedef __bf16 v8bf __attribute__((ext_vector_type(8)));
typedef float  v4f  __attribute__((ext_vector_type(4)));

static __device__ __forceinline__ v4f mfma16(v8bf a, v8bf b, v4f c) {
  return __builtin_amdgcn_mfma_f32_16x16x32_bf16(a, b, c, 0, 0, 0);
}

static __device__ __forceinline__ v8bf cvt8(const float* __restrict__ p) {
  float4 a = *(const float4*)p;
  float4 b = *(const float4*)(p + 4);
  v8bf f;
  f[0] = (__bf16)a.x; f[1] = (__bf16)a.y; f[2] = (__bf16)a.z; f[3] = (__bf16)a.w;
  f[4] = (__bf16)b.x; f[5] = (__bf16)b.y; f[6] = (__bf16)b.z; f[7] = (__bf16)b.w;
  return f;
}

static __device__ __forceinline__ v8bf cvt2x4(float4 a, float4 b) {
  v8bf f;
  f[0] = (__bf16)a.x; f[1] = (__bf16)a.y; f[2] = (__bf16)a.z; f[3] = (__bf16)a.w;
  f[4] = (__bf16)b.x; f[5] = (__bf16)b.y; f[6] = (__bf16)b.z; f[7] = (__bf16)b.w;
  return f;
}

// ---------------- prep + conv merged (5 blocks)
__global__ __launch_bounds__(256)
void prep_conv_kernel(const float* __restrict__ query,
                      const float* __restrict__ g1, const float* __restrict__ b1,
                      const float* __restrict__ Wq, const float* __restrict__ bq,
                      const float* __restrict__ Wk, const float* __restrict__ bk,
                      const float* __restrict__ Wv, const float* __restrict__ Wp,
                      const float* __restrict__ Wf1, const float* __restrict__ Wf2,
                      __bf16* __restrict__ qw, float* __restrict__ qb,
                      __bf16* __restrict__ wdst)
{
  __shared__ float qn[8*128];
  __shared__ float qp[8*128];
  const int t = threadIdx.x;
  const int m = blockIdx.x;
  if (m < 4) {  // weight prefold
    const float* src = (m == 0) ? Wv : (m == 1) ? Wp : (m == 2) ? Wf1 : Wf2;
    __bf16* d = wdst + m*16384;
    for (int i = t; i < 2048; i += 256)
      *(v8bf*)&d[i*8] = cvt8(&src[i*8]);
    return;
  }
  // ---- prep (block 4)
  for (int idx = t; idx < 1024; idx += 256) qn[idx] = query[idx];
  __syncthreads();
  {
    const int w = t >> 6, L = t & 63;
    const int row = 2*w + (L >> 5), col = L & 31;
    float x[4], s = 0.f, sq = 0.f;
    for (int p = 0; p < 4; p++) { x[p] = qn[row*128 + col + 32*p]; s += x[p]; sq += x[p]*x[p]; }
    for (int mm = 1; mm < 32; mm <<= 1) { s += __shfl_xor(s, mm); sq += __shfl_xor(sq, mm); }
    const float mean = s * (1.f/128.f);
    const float var  = sq * (1.f/128.f) - mean*mean;
    const float rs   = rsqrtf(var + 1e-5f);
    for (int p = 0; p < 4; p++) {
      const int e = col + 32*p;
      qn[row*128 + e] = (x[p]-mean)*rs*g1[e] + b1[e];
    }
  }
  __syncthreads();
  {
    const int i = t >> 5, o0 = t & 31;
    for (int p = 0; p < 4; p++) {
      const int o = o0 + 32*p;
      float acc = bq[o];
      for (int e = 0; e < 128; e++) acc += qn[i*128 + e] * Wq[o*128 + e];
      qp[i*128 + o] = acc;
    }
  }
  __syncthreads();
  {
    const int cc = t >> 2, e0 = (t & 3) * 32;
    const int h = cc >> 3, i = cc & 7;
    float qv[16];
    for (int d = 0; d < 16; d++) qv[d] = qp[i*128 + 16*h + d];
    for (int e = e0; e < e0 + 32; e++) {
      float acc = 0.f;
      for (int d = 0; d < 16; d++) acc += qv[d] * Wk[(16*h + d)*128 + e];
      qw[cc*136 + e] = (__bf16)(0.25f * acc);
    }
    if (t < 64) {
      const int h2 = t >> 3, i2 = t & 7;
      float acc = 0.f;
      for (int d = 0; d < 16; d++) acc += qp[i2*128 + 16*h2 + d] * bk[16*h2 + d];
      qb[t] = 0.25f * acc;
    }
  }
}

// ---------------- fully fused: 8 batches/block, attn (pipelined) + MLP
__global__ __launch_bounds__(256, 4)
void fused2_kernel(const float* __restrict__ tgt,
                   const float* __restrict__ query,
                   const float* __restrict__ qb,
                   const float* __restrict__ bv,
                   const float* __restrict__ bp,
                   const float* __restrict__ g2, const float* __restrict__ b2,
                   const float* __restrict__ bf1, const float* __restrict__ bf2,
                   const __bf16* __restrict__ qw,
                   const __bf16* __restrict__ wv,
                   const __bf16* __restrict__ wp,
                   const __bf16* __restrict__ wf1,
                   const __bf16* __restrict__ wf2,
                   float* __restrict__ out)
{
  // LDS map (bytes):
  //  [0      , 26112) s_tgt  2 x [48][136] bf16 (double buffer)    | phase B: s_h  (17408)
  //  [26112  , 35328) s_P    [64][72]  bf16 (wave-private rows)
  //  [35328  , 53760) s_vT   [128][72] bf16 (wave-private rows)    | phase B: s_xn (17408)
  //  [53760  , 71168) s_act  [64][136] bf16 (phase A write / B read)
  __shared__ __align__(16) char smem[71168];
  __bf16* const s_tgt0 = (__bf16*)smem;
  __bf16* const s_P    = (__bf16*)(smem + 26112);
  __bf16* const s_vT   = (__bf16*)(smem + 35328);
  __bf16* const s_act  = (__bf16*)(smem + 53760);
  __bf16* const s_h    = (__bf16*)smem;            // alias, used after final barrier
  __bf16* const s_xn   = (__bf16*)(smem + 35328);  // alias, used after final barrier

  const int t  = threadIdx.x;
  const int w  = t >> 6;       // wave 0..3
  const int L  = t & 63;
  const int ln = L & 15;       // MFMA m/n lane
  const int g  = L >> 4;       // quad (k-slice index)
  const long b0 = (long)blockIdx.x * 8;

  // zero j-pads [48,64) of this wave's s_P/s_vT rows (never overwritten later)
  for (int p = 0; p < 8; p++) {
    const int idx = 64*p + L;
    s_vT[(w*32 + (idx >> 4))*72 + 48 + (idx & 15)] = (__bf16)0.f;
  }
  for (int p = 0; p < 4; p++) {
    const int idx = 64*p + L;
    s_P[(w*16 + (idx >> 4))*72 + 48 + (idx & 15)] = (__bf16)0.f;
  }

  const int c = w*16 + ln;     // dots column (h*8+i)
  const float qbv = qb[c];
  const int qi = c & 7;
  const bool allv = (qi < 2);
  int hsp = 0, wsp = 0;
  if (!allv) { const int idx = qi - 2; hsp = idx / 3; wsp = idx - 3*hsp; }

  // prologue: prefetch batch 0 into registers
  float4 pf[6];
  {
    const float* tg = tgt + b0 * 6144;
#pragma unroll
    for (int k2 = 0; k2 < 3; k2++) {
      pf[2*k2]   = *(const float4*)&tg[(t + k2*256)*8];
      pf[2*k2+1] = *(const float4*)&tg[(t + k2*256)*8 + 4];
    }
  }

  for (int bi = 0; bi < 8; bi++) {
    __bf16* const s_tgt = s_tgt0 + (bi & 1) * 6528;   // 13056 B buffers

    // stage prefetched regs -> LDS (fp32 -> bf16)
#pragma unroll
    for (int k2 = 0; k2 < 3; k2++) {
      const int c8 = t + k2*256;
      *(v8bf*)&s_tgt[(c8 >> 4)*136 + (c8 & 15)*8] = cvt2x4(pf[2*k2], pf[2*k2+1]);
    }
    __syncthreads();   // the ONLY barrier per batch (double buffer covers WAR)

    // prefetch next batch — latency hides under dots/softmax/PV below
    if (bi < 7) {
      const float* tg = tgt + (b0 + bi + 1) * 6144;
#pragma unroll
      for (int k2 = 0; k2 < 3; k2++) {
        pf[2*k2]   = *(const float4*)&tg[(t + k2*256)*8];
        pf[2*k2+1] = *(const float4*)&tg[(t + k2*256)*8 + 4];
      }
    }

    // dots = tgt@QW.T  and  v = tgt@Wv.T
    v4f dacc[3], vacc[3][2];
    {
      v8bf qwf[4], wvf[2][4];
      for (int ks = 0; ks < 4; ks++)
        qwf[ks] = *(const v8bf*)&qw[c*136 + ks*32 + g*8];
      for (int nt = 0; nt < 2; nt++)
        for (int ks = 0; ks < 4; ks++)
          wvf[nt][ks] = *(const v8bf*)&wv[(w*32 + nt*16 + ln)*128 + ks*32 + g*8];
      const v4f z = {0.f, 0.f, 0.f, 0.f};
      for (int mt = 0; mt < 3; mt++) { dacc[mt] = z; vacc[mt][0] = z; vacc[mt][1] = z; }
      for (int mt = 0; mt < 3; mt++) {
        v8bf af[4];
        for (int ks = 0; ks < 4; ks++)
          af[ks] = *(const v8bf*)&s_tgt[(mt*16 + ln)*136 + ks*32 + g*8];
        for (int ks = 0; ks < 4; ks++) {
          dacc[mt]    = mfma16(af[ks], qwf[ks],    dacc[mt]);
          vacc[mt][0] = mfma16(af[ks], wvf[0][ks], vacc[mt][0]);
          vacc[mt][1] = mfma16(af[ks], wvf[1][ks], vacc[mt][1]);
        }
      }
    }

    // softmax over j (window-masked) -> wave-private s_P / s_vT
    {
      float dv[12];
      float mx = -1e30f;
      for (int mt = 0; mt < 3; mt++)
        for (int r = 0; r < 4; r++) {
          const int j  = mt*16 + g*4 + r;
          const int rr = j / 6, ccol = j - rr*6;
          const bool valid = allv || (((rr >> 2) == hsp) && ((ccol >> 1) == wsp));
          const float dd = valid ? dacc[mt][r] + qbv : -1e30f;
          dv[mt*4 + r] = dd;
          mx = fmaxf(mx, dd);
        }
      mx = fmaxf(mx, __shfl_xor(mx, 16));
      mx = fmaxf(mx, __shfl_xor(mx, 32));
      float sm = 0.f;
      for (int p = 0; p < 12; p++) {
        const float e = (dv[p] > -1e29f) ? __expf(dv[p] - mx) : 0.f;
        dv[p] = e; sm += e;
      }
      sm += __shfl_xor(sm, 16);
      sm += __shfl_xor(sm, 32);
      const float inv = 1.f / sm;
      for (int mt = 0; mt < 3; mt++)
        for (int r = 0; r < 4; r++)
          s_P[c*72 + mt*16 + g*4 + r] = (__bf16)(dv[mt*4 + r] * inv);
      for (int nt = 0; nt < 2; nt++) {
        const int o = w*32 + nt*16 + ln;
        const float bvo = bv[o];
        for (int mt = 0; mt < 3; mt++)
          for (int r = 0; r < 4; r++)
            s_vT[o*72 + mt*16 + g*4 + r] = (__bf16)(vacc[mt][nt][r] + bvo);
      }
    }
    // no barrier: s_P rows [16w,16w+16) and s_vT rows [32w,32w+32) are wave-private

    // PV — both n-quadrants (B-fragment col must be g-independent); select at store
    {
      const v4f z = {0.f,0.f,0.f,0.f};
      v4f oacc[2] = {z, z};
      for (int ks = 0; ks < 2; ks++) {
        v8bf pfrag = *(const v8bf*)&s_P[(w*16 + ln)*72 + ks*32 + g*8];
        for (int nt = 0; nt < 2; nt++) {
          v8bf vf = *(const v8bf*)&s_vT[(w*32 + nt*16 + ln)*72 + ks*32 + g*8];
          oacc[nt] = mfma16(pfrag, vf, oacc[nt]);
        }
      }
      const int ntv = g >> 1;               // head of rows g*4+r matches col chunk
      const int o = w*32 + ntv*16 + ln;
      for (int r = 0; r < 4; r++) {
        const int i = (g*4 + r) & 7;
        s_act[(bi*8 + i)*136 + o] = (__bf16)oacc[ntv][r];
      }
    }
    // no trailing barrier: next iteration writes the OTHER s_tgt buffer; a wave
    // writes buf[x] in iter i+2 only after exiting barrier_{i+1}, which all waves
    // enter only after finishing their iter-i reads of buf[x].
  }
  __syncthreads();   // s_act cross-wave + alias handoff (s_tgt/s_vT die here)

  // ---- MLP on the 64 act rows; wave owns rows [16w,16w+16) (= 2 batches)
  float* base = out + ((long)blockIdx.x*64 + w*16)*128;

  v8bf af[4];
  for (int ks = 0; ks < 4; ks++)
    af[ks] = *(const v8bf*)&s_act[(w*16 + ln)*136 + ks*32 + g*8];

  // GEMM1: x = act@Wp.T + bp + query
  float x[8][4];
  for (int nt = 0; nt < 8; nt++) {
    v4f acc = {0.f, 0.f, 0.f, 0.f};
    for (int ks = 0; ks < 4; ks++) {
      v8bf wf = *(const v8bf*)&wp[(nt*16 + ln)*128 + ks*32 + g*8];
      acc = mfma16(af[ks], wf, acc);
    }
    const int col = nt*16 + ln;
    const float bpv = bp[col];
    for (int r = 0; r < 4; r++)
      x[nt][r] = acc[r] + bpv + query[((4*g + r) & 7)*128 + col];
  }

  // LN per row (rows 4g+r wave-local: reduce over nt then 16 lanes)
  float rmean[4], rrs[4];
  for (int r = 0; r < 4; r++) {
    float s = 0.f, sq = 0.f;
    for (int nt = 0; nt < 8; nt++) { s += x[nt][r]; sq += x[nt][r]*x[nt][r]; }
    for (int mm = 1; mm < 16; mm <<= 1) { s += __shfl_xor(s, mm); sq += __shfl_xor(sq, mm); }
    const float mean = s * (1.f/128.f);
    const float var  = sq * (1.f/128.f) - mean*mean;
    rmean[r] = mean;
    rrs[r]   = rsqrtf(var + 1e-5f);
  }
  for (int nt = 0; nt < 8; nt++) {
    const int col = nt*16 + ln;
    const float gv = g2[col], b2v = b2[col];
    for (int r = 0; r < 4; r++)
      s_xn[w*2176 + (4*g + r)*136 + col] = (__bf16)((x[nt][r] - rmean[r])*rrs[r]*gv + b2v);
  }
  // wave-private transpose roundtrip (no barrier)
  v8bf xf[4];
  for (int ks = 0; ks < 4; ks++)
    xf[ks] = *(const v8bf*)&s_xn[w*2176 + ln*136 + ks*32 + g*8];

  // GEMM2: h = gelu(xn@Wf1.T + bf1)
  for (int nt = 0; nt < 8; nt++) {
    v4f acc = {0.f, 0.f, 0.f, 0.f};
    for (int ks = 0; ks < 4; ks++) {
      v8bf wf = *(const v8bf*)&wf1[(nt*16 + ln)*128 + ks*32 + g*8];
      acc = mfma16(xf[ks], wf, acc);
    }
    const int col = nt*16 + ln;
    const float b1v = bf1[col];
    for (int r = 0; r < 4; r++) {
      const float xx = acc[r] + b1v;
      s_h[w*2176 + (4*g + r)*136 + col] = (__bf16)(0.5f*xx*(1.f + erff(xx*0.70710678118654752f)));
    }
  }
  v8bf hf[4];
  for (int ks = 0; ks < 4; ks++)
    hf[ks] = *(const v8bf*)&s_h[w*2176 + ln*136 + ks*32 + g*8];

  // GEMM3: y = h@Wf2.T + bf2 ; out = x + y
  for (int nt = 0; nt < 8; nt++) {
    v4f acc = {0.f, 0.f, 0.f, 0.f};
    for (int ks = 0; ks < 4; ks++) {
      v8bf wf = *(const v8bf*)&wf2[(nt*16 + ln)*128 + ks*32 + g*8];
      acc = mfma16(hf[ks], wf, acc);
    }
    const int col = nt*16 + ln;
    const float b2v = bf2[col];
    for (int r = 0; r < 4; r++)
      base[(4*g + r)*128 + col] = x[nt][r] + acc[r] + b2v;
  }
}

extern "C" void kernel_launch(void* const* d_in, const int* in_sizes, int n_in,
                              void* d_out, int out_size, void* d_ws, size_t ws_size,
                              hipStream_t stream)
{
  const float* query = (const float*)d_in[0];
  const float* tgt   = (const float*)d_in[1];
  const float* g1    = (const float*)d_in[2];
  const float* b1    = (const float*)d_in[3];
  const float* Wq    = (const float*)d_in[4];
  const float* bq    = (const float*)d_in[5];
  const float* Wk    = (const float*)d_in[6];
  const float* bk    = (const float*)d_in[7];
  const float* Wv    = (const float*)d_in[8];
  const float* bv    = (const float*)d_in[9];
  const float* Wp    = (const float*)d_in[10];
  const float* bp    = (const float*)d_in[11];
  const float* g2    = (const float*)d_in[12];
  const float* b2    = (const float*)d_in[13];
  const float* Wf1   = (const float*)d_in[14];
  const float* bf1   = (const float*)d_in[15];
  const float* Wf2   = (const float*)d_in[16];
  const float* bf2   = (const float*)d_in[17];
  float* out = (float*)d_out;

  // workspace: qw (64x136 bf16) | qb (64 f32) | Wv,Wp,Wf1,Wf2 prefolded bf16
  __bf16* qw  = (__bf16*)d_ws;                           // 17408 B
  float*  qb  = (float*)((char*)d_ws + 64*136*2);        // 256 B
  __bf16* wbf = (__bf16*)((char*)d_ws + 64*136*2 + 256); // 4 * 32768 B (16B-aligned)

  const int nB = in_sizes[1] / (48 * 128);               // 16384

  prep_conv_kernel<<<5, 256, 0, stream>>>(query, g1, b1, Wq, bq, Wk, bk,
                                          Wv, Wp, Wf1, Wf2, qw, qb, wbf);
  fused2_kernel<<<nB/8, 256, 0, stream>>>(tgt, query, qb, bv, bp, g2, b2,
                                          bf1, bf2, qw,
                                          wbf, wbf + 16384, wbf + 2*16384, wbf + 3*16384,
                                          out);
}